// Round 4
// baseline (566.148 us; speedup 1.0000x reference)
//
#include <hip/hip_runtime.h>
#include <math.h>

#define NB 32
#define NT 512
#define NC 4233
#define NU 64
#define LABT 129            // 2*NU+1
#define PADV (-3.4028234663852886e38f)   // float32 min (matches jnp.finfo(f32).min)
#define EMITP_N (NB * NT * 128)

typedef __attribute__((address_space(3))) unsigned int lu32;
typedef __attribute__((address_space(1))) unsigned int gu32;

// ---------------------------------------------------------------------------
// Kernel 0: massively-parallel emission gather (prep folded in).
// emitP[b][t][j] = logit[b][t][ext_col(j)]   for j = 0..127.
// ext_col(128) == blank == ext_col(0): recovered in the scan via readfirstlane.
// ---------------------------------------------------------------------------
__global__ __launch_bounds__(256)
void ctc_gather_kernel(const float* __restrict__ logit,   // [B][T][C]
                       const int*   __restrict__ label,   // [U][B]
                       const int*   __restrict__ blank_ptr,
                       float*       __restrict__ emitP)   // [B][T][128]
{
    int tid = blockIdx.x * 256 + threadIdx.x;
    if (tid >= EMITP_N) return;
    int bt = tid >> 7;               // b*NT + t
    int j  = tid & 127;
    int b  = bt / NT;
    int blank = blank_ptr[0];
    int col;
    if (j & 1) {
        int raw = label[((j - 1) >> 1) * NB + b];
        int ev  = (raw == blank) ? -1 : raw;
        col = ev % NC;                 // python floor-mod for -1 pad labels
        if (col < 0) col += NC;
    } else {
        col = blank;
    }
    emitP[tid] = logit[(size_t)bt * NC + col];
}

// ---------------------------------------------------------------------------
// Cross-lane shift-by-1 via DPP wave_shr:1 -- pure VALU, no lgkmcnt.
// ---------------------------------------------------------------------------
__device__ __forceinline__ float dpp_wave_shr1(float x, float fill) {
    return __int_as_float(__builtin_amdgcn_update_dpp(
        __float_as_int(fill), __float_as_int(x), 0x138 /*wave_shr:1*/,
        0xf, 0xf, false));
}

// ---------------------------------------------------------------------------
// Kernel 1: single-wave DP scan, LDS chunk-staged.
// Emission rows stream HBM->LDS in 32KB chunks (64 t-rows) via
// global_load_lds, double-buffered; the recurrence reads ds_read_b64 only.
// Lane l holds dp[2l], dp[2l+1]; lane 63 also dp[128].
// ---------------------------------------------------------------------------
__global__ __launch_bounds__(64)
void ctc_scan_kernel(const float* __restrict__ emitP,  // [B][T][128]
                     const int*   __restrict__ label,  // [U][B]
                     const int*   __restrict__ blank_ptr,
                     float* __restrict__ out,          // [B][T][LABT] align
                     float* __restrict__ loss_out)     // [B]
{
    __shared__ __align__(16) char stage[65536];                 // 2 x 32KB
    __shared__ __align__(16) unsigned long long bpm[NT][4];     // backptr masks
    __shared__ int   wl[NT];
    __shared__ float fdp[132];

    const int b = blockIdx.x;
    const int l = threadIdx.x;
    const int blank = blank_ptr[0];

    // label-derived state
    int raw = label[l * NB + b];
    unsigned long long nbmask = __ballot(raw != blank);
    const int Y = 2 * (int)__popcll(nbmask) + 1;
    int ev  = (raw == blank) ? -1 : raw;
    int pev = __shfl_up(ev, 1);
    if (l == 0) pev = -1;
    const bool cndO = (ev == blank) || (ev == pev);   // cond for odd j=2l+1

    const char* gbase = (const char*)(emitP + (size_t)b * NT * 128);

// chunk k (64 t-rows, 32KB) -> stage half (k&1).  32 x 16B-wide DMA ops.
#define STAGE_CHUNK(k)                                                         \
    do {                                                                       \
        const char* gsrc_ = gbase + (size_t)(k) * 32768 + l * 16;              \
        char* ldst_ = stage + (((k) & 1) << 15);                               \
        _Pragma("unroll")                                                      \
        for (int i_ = 0; i_ < 32; ++i_) {                                      \
            __builtin_amdgcn_global_load_lds(                                  \
                (const gu32*)(gsrc_ + i_ * 1024),                              \
                (lu32*)(ldst_ + i_ * 1024), 16, 0, 0);                         \
        }                                                                      \
    } while (0)

#define WAITVM(n)                                                              \
    do { asm volatile("s_waitcnt vmcnt(" #n ")" ::: "memory");                 \
         __builtin_amdgcn_sched_barrier(0); } while (0)
#define WAITLGKM0                                                              \
    do { asm volatile("s_waitcnt lgkmcnt(0)" ::: "memory");                    \
         __builtin_amdgcn_sched_barrier(0); } while (0)

// LDS address of this lane's float2 of row p (p may run past 511: wraps
// harmlessly into valid stage memory, value never consumed)
#define ROWPTR(p) ((const float2*)(stage + ((((p) >> 6) & 1) << 15)            \
                                         + (((p) & 63) << 9)) + l)

    // prologue: chunks 0 and 1 in flight
    STAGE_CHUNK(0);
    STAGE_CHUNK(1);
    WAITVM(32);                       // chunk 0 resident (chunk 1 outstanding)

    // t = 0 init (from LDS row 0)
    float2 e00 = *ROWPTR(0);
    float v0 = (l == 0) ? e00.x : PADV;   // dp[2l]
    float v1 = (l == 0) ? e00.y : PADV;   // dp[2l+1]
    float v2 = PADV;                      // dp[128] (lane 63 meaningful)

    // 4-deep register ring from LDS; slot = t & 3
    float2 q1 = *ROWPTR(1), q2 = *ROWPTR(2), q3 = *ROWPTR(3), q0 = *ROWPTR(4);

#define STEPL(t_, rr)                                                          \
    do {                                                                       \
        float u1 = dpp_wave_shr1(v1, PADV);   /* dp[2l-1] */                   \
        /* even j=2l: 2-way lse (bit-exact 1-exp form) */                      \
        float mE   = fmaxf(v0, u1);                                            \
        float lseE = mE + logf(1.0f + expf(-fabsf(v0 - u1)));                  \
        unsigned long long bE = __ballot(v0 < u1);                             \
        /* odd j=2l+1: 3-way lse, exact rounds-0..3 expression */              \
        float c2e = cndO ? PADV : u1;                                          \
        float mO  = fmaxf(fmaxf(v1, v0), c2e);                                 \
        float lseO = mO + logf(expf(v1 - mO) + expf(v0 - mO) + expf(c2e - mO));\
        unsigned long long gAB = __ballot(v1 >= v0);                           \
        unsigned long long gAC = __ballot(v1 >= c2e);                          \
        unsigned long long gBC = __ballot(v0 >= c2e);                          \
        /* j=128: 2-way lse on lane63's (v2, v1) */                            \
        float mL   = fmaxf(v2, v1);                                            \
        float lseL = mL + logf(1.0f + expf(-fabsf(v2 - v1)));                  \
        unsigned long long bL = __ballot(v2 < v1);                             \
        /* e[128] == e[0] == lane0's rr.x (blank column) */                    \
        float eL = __int_as_float(                                             \
            __builtin_amdgcn_readfirstlane(__float_as_int(rr.x)));             \
        v0 = rr.x + lseE;                                                      \
        v1 = rr.y + lseO;                                                      \
        v2 = eL   + lseL;                                                      \
        if (l == 0) {                                                          \
            unsigned long long t0m = gAB & gAC;                                \
            ulonglong2 w01, w23;                                               \
            w01.x = bE;          w01.y = ~t0m & gBC;                           \
            w23.x = ~t0m & ~gBC; w23.y = (bL >> 63);                           \
            *(ulonglong2*)&bpm[t_][0] = w01;                                   \
            *(ulonglong2*)&bpm[t_][2] = w23;                                   \
        }                                                                      \
        rr = *ROWPTR((t_) + 4);   /* prefetch; past-end wraps, unused */       \
    } while (0)

    // chunk 0 body: t = 1..59
    STEPL(1, q1); STEPL(2, q2); STEPL(3, q3);
    for (int tb = 4; tb < 60; tb += 4) {
        STEPL(tb, q0); STEPL(tb + 1, q1); STEPL(tb + 2, q2); STEPL(tb + 3, q3);
    }
    // 7 chunk boundaries; segment after boundary c covers t = 60+64c .. 123+64c
    for (int c = 0; c < 7; ++c) {
        WAITLGKM0;                 // all ds_reads of the freed buffer drained
        WAITVM(0);                 // chunk c+1 resident (issued ~64 steps ago)
        if (c < 6) STAGE_CHUNK(c + 2);
        const int base = 60 + (c << 6);
        for (int tb = base; tb < base + 64; tb += 4) {
            STEPL(tb, q0); STEPL(tb + 1, q1); STEPL(tb + 2, q2); STEPL(tb + 3, q3);
        }
    }
    // tail: t = 508..511
    STEPL(508, q0); STEPL(509, q1); STEPL(510, q2); STEPL(511, q3);
#undef STEPL

    // publish final dp row
    fdp[2 * l]     = v0;
    fdp[2 * l + 1] = v1;
    if (l == 63) fdp[128] = v2;
    __syncthreads();

    // zero-fill align output (overlaps with lane0 backtrack drain)
    float* outA = out + (size_t)b * (NT * LABT);
    {
        float4 z4; z4.x = 0.f; z4.y = 0.f; z4.z = 0.f; z4.w = 0.f;
        float4* o4 = (float4*)outA;
        for (int p = l; p < (NT * LABT) / 4; p += 64) o4[p] = z4;
    }

    // loss + register-ring Viterbi backtrack (lane 0)
    if (l == 0) {
        int i2 = Y - 2; if (i2 < 0) i2 += LABT;   // python wrap for yl==1
        float d1 = fdp[Y - 1];
        float d2 = fdp[i2];
        float mm = fmaxf(d1, d2);
        float la = mm + logf(expf(d1 - mm) + expf(d2 - mm));
        loss_out[b] = -la * 2.0f / (float)(Y - 1);

        int w = (d1 > d2) ? (Y - 1) : i2;
        const ulonglong2* bp2 = (const ulonglong2*)&bpm[0][0];  // 2 per row

#define BLOAD(qa, qb, row) do { qa = bp2[2 * (row)]; qb = bp2[2 * (row) + 1]; } while (0)
#define BPROC(qa, qb, row) do {                                                \
        wl[row] = w;                                                           \
        int lw_ = w >> 1;                                                      \
        int dE_ = (w == 128) ? (int)qb.y : (int)((qa.x >> lw_) & 1ULL);        \
        int dO_ = (int)((qa.y >> lw_) & 1ULL) + 2 * (int)((qb.x >> lw_) & 1ULL);\
        w -= (w & 1) ? dO_ : dE_;                                              \
    } while (0)

        ulonglong2 a0, b0, a1, b1, a2, b2, a3, b3;
        BLOAD(a0, b0, NT - 1);
        BLOAD(a1, b1, NT - 2);
        BLOAD(a2, b2, NT - 3);
        BLOAD(a3, b3, NT - 4);
        int tt;
        for (tt = NT - 1; tt >= 8; tt -= 4) {
            BPROC(a0, b0, tt    ); BLOAD(a0, b0, tt - 4);
            BPROC(a1, b1, tt - 1); BLOAD(a1, b1, tt - 5);
            BPROC(a2, b2, tt - 2); BLOAD(a2, b2, tt - 6);
            BPROC(a3, b3, tt - 3); BLOAD(a3, b3, tt - 7);
        }
        // slots now hold rows 7,6,5,4
        BPROC(a0, b0, 7); BLOAD(a0, b0, 3);
        BPROC(a1, b1, 6); BLOAD(a1, b1, 2);
        BPROC(a2, b2, 5); BLOAD(a2, b2, 1);
        BPROC(a3, b3, 4);
        BPROC(a0, b0, 3);
        BPROC(a1, b1, 2);
        BPROC(a2, b2, 1);
        wl[0] = w;   // bp at t=0 is identity
#undef BLOAD
#undef BPROC
    }
    __syncthreads();   // drain zero stores + publish wl

    // scatter the ones
    for (int t2 = l; t2 < NT; t2 += 64)
        outA[(size_t)t2 * LABT + wl[t2]] = 1.0f;
}

// ---------------------------------------------------------------------------
extern "C" void kernel_launch(void* const* d_in, const int* in_sizes, int n_in,
                              void* d_out, int out_size, void* d_ws, size_t ws_size,
                              hipStream_t stream)
{
    const float* logit = (const float*)d_in[0];
    const int*   label = (const int*)d_in[1];
    const int*   blank = (const int*)d_in[2];

    float* out = (float*)d_out;   // [B*T*LABT] align (0/1 float) then [B] loss

    float* emitP = (float*)d_ws;  // 32*512*128 floats = 8.39 MB

    ctc_gather_kernel<<<EMITP_N / 256, 256, 0, stream>>>(
        logit, label, blank, emitP);
    ctc_scan_kernel<<<NB, 64, 0, stream>>>(
        emitP, label, blank, out, out + (size_t)NB * NT * LABT);
}